// Round 4
// baseline (276.120 us; speedup 1.0000x reference)
//
#include <hip/hip_runtime.h>
#include <hip/hip_bf16.h>

// CouplingSplineLayer fused kernel for MI355X (gfx950), round 4.
// GEMM1(8->256)+relu -> GEMM2(256->256)+relu -> GEMM3(256->184) -> RQ spline.
// R4: 32-row tiles, 512 threads, LDS 33.8 KB -> 4 blocks/CU (was 2).
// R1-R3 showed neither MFMA (26%) nor VALU (47%) nor DS nor HBM saturated:
// barrier-serialized phases with only 2 resident blocks/CU = latency-bound.
// 4 staggered blocks/CU fill each other's barrier drains (m114 co-schedule).
// G2 splits hidden 8-way (W1 read once/block); G3 splits 12 n-tiles
// {2,2,2,2,1,1,1,1} (Wout once/block) to hold L2 weight traffic flat.

typedef __bf16 bf16x8 __attribute__((ext_vector_type(8)));
typedef __bf16 bf16x4 __attribute__((ext_vector_type(4)));
typedef float  f32x4  __attribute__((ext_vector_type(4)));

#define MFMA16(a,b,c) __builtin_amdgcn_mfma_f32_16x16x32_bf16((a),(b),(c),0,0,0)

// swizzled weight regions (bf16 element offsets in d_ws); frag layout identical
// for A-use (transposed G1/G2) and B-use (G3):
// elem W[k][n] at sw[((kb*NT + tile)*64 + lane)*8 + j], k=kb*32+(lane>>4)*8+j, n=tile*16+(lane&15)
#define SW_W1_OFF 8192      // W0: 1 kb * 16 tiles * 512
#define SW_WO_OFF 73728     // W1: 8 kb * 16 tiles * 512
#define SW_TOTAL  122880    // Wout: 8 kb * 12 tiles * 512

#define ROWS    32          // batch rows per block
#define HSTRIDE 264         // h row stride in bf16 (528 B: 16B-aligned, 4-bank rot/row)

__global__ void prep_kernel(const float* __restrict__ W0,
                            const float* __restrict__ W1,
                            const float* __restrict__ Wout,
                            __bf16* __restrict__ sw)
{
  int i = blockIdx.x * 256 + threadIdx.x;
  if (i >= SW_TOTAL) return;
  const float* src; int K, N, NT, li;
  if (i < SW_W1_OFF)      { src = W0;   K = 8;   N = 256; NT = 16; li = i; }
  else if (i < SW_WO_OFF) { src = W1;   K = 256; N = 256; NT = 16; li = i - SW_W1_OFF; }
  else                    { src = Wout; K = 256; N = 184; NT = 12; li = i - SW_WO_OFF; }
  int j    = li & 7;
  int l    = (li >> 3) & 63;
  int rest = li >> 9;
  int nt   = rest % NT;
  int kb   = rest / NT;
  int k = kb * 32 + ((l >> 4) << 3) + j;
  int n = nt * 16 + (l & 15);
  float v = (k < K && n < N) ? src[k * N + n] : 0.0f;
  sw[i] = (__bf16)v;
}

__global__ __launch_bounds__(512, 8)
void fused_kernel(const float* __restrict__ x,
                  const float* __restrict__ b0v,
                  const float* __restrict__ b1v,
                  const float* __restrict__ boutv,
                  const __bf16* __restrict__ sw,
                  float* __restrict__ out,
                  int nrows)
{
  // [0, 16896)      h1 (32 x HSTRIDE bf16), later aliased by raw (32 x HSTRIDE)
  // [16896, 33792)  h2 (32 x HSTRIDE bf16), later aliased by ldet (256 f32)
  __shared__ __align__(16) unsigned char smem[2 * ROWS * HSTRIDE * 2];
  __bf16* h1   = (__bf16*)smem;
  __bf16* h2   = (__bf16*)(smem + ROWS * HSTRIDE * 2);
  __bf16* rawb = h1;
  float*  ldet = (float*)h2;

  const int tid  = threadIdx.x;
  const int wave = tid >> 6;
  const int lane = tid & 63;
  const int quad = lane >> 4;
  const int l16  = lane & 15;
  const int row0 = blockIdx.x * ROWS;

  const __bf16* swW1 = sw + SW_W1_OFF;
  const __bf16* swWo = sw + SW_WO_OFF;
  const f32x4 z4 = {0.f, 0.f, 0.f, 0.f};

  // ---- GEMM1 (transposed): h1[b][m] = relu(sum_k W0[k][m]*x2[b][k] + b0[m])
  // m split 8-way (wave -> 2 m-tiles), both batch tiles per wave.
  {
    bf16x8 bfr[2];
    #pragma unroll
    for (int nt = 0; nt < 2; nt++){
      bf16x8 b = {};                       // k=quad*8+j; only quad 0 (k<8) real,
      if (quad == 0){                      // W0 frags zero-padded past k=8
        const float* xp = x + (long)(row0 + nt*16 + l16)*16 + 8;
        float4 u = *(const float4*)xp;
        float4 v = *(const float4*)(xp + 4);
        b[0]=(__bf16)u.x; b[1]=(__bf16)u.y; b[2]=(__bf16)u.z; b[3]=(__bf16)u.w;
        b[4]=(__bf16)v.x; b[5]=(__bf16)v.y; b[6]=(__bf16)v.z; b[7]=(__bf16)v.w;
      }
      bfr[nt] = b;
    }
    #pragma unroll
    for (int mi = 0; mi < 2; mi++){
      int mt = wave*2 + mi;
      bf16x8 a = *(const bf16x8*)(sw + (mt*64 + lane)*8);
      f32x4 acc0 = MFMA16(a, bfr[0], z4);
      f32x4 acc1 = MFMA16(a, bfr[1], z4);
      float4 bb = *(const float4*)(b0v + mt*16 + quad*4);   // bias along m
      bf16x4 p0, p1;
      p0[0]=(__bf16)fmaxf(acc0[0]+bb.x,0.f); p0[1]=(__bf16)fmaxf(acc0[1]+bb.y,0.f);
      p0[2]=(__bf16)fmaxf(acc0[2]+bb.z,0.f); p0[3]=(__bf16)fmaxf(acc0[3]+bb.w,0.f);
      p1[0]=(__bf16)fmaxf(acc1[0]+bb.x,0.f); p1[1]=(__bf16)fmaxf(acc1[1]+bb.y,0.f);
      p1[2]=(__bf16)fmaxf(acc1[2]+bb.z,0.f); p1[3]=(__bf16)fmaxf(acc1[3]+bb.w,0.f);
      *(bf16x4*)(h1 + (0*16 + l16)*HSTRIDE + mt*16 + quad*4) = p0;
      *(bf16x4*)(h1 + (1*16 + l16)*HSTRIDE + mt*16 + quad*4) = p1;
    }
  }
  __syncthreads();

  // ---- GEMM2 (transposed): h2[b][m] = relu(sum_k W1[k][m]*h1[b][k] + b1[m])
  // m split 8-way: W1 frags read exactly once per block.
  {
    f32x4 acc[2][2];
    #pragma unroll
    for (int mi=0;mi<2;mi++){ acc[mi][0]=z4; acc[mi][1]=z4; }
    #pragma unroll
    for (int kb=0;kb<8;kb++){
      bf16x8 bfr[2];
      #pragma unroll
      for (int nt=0;nt<2;nt++)
        bfr[nt] = *(const bf16x8*)(h1 + (nt*16 + l16)*HSTRIDE + kb*32 + quad*8);
      #pragma unroll
      for (int mi=0;mi<2;mi++){
        bf16x8 a = *(const bf16x8*)(swW1 + ((kb*16 + wave*2 + mi)*64 + lane)*8);
        acc[mi][0] = MFMA16(a, bfr[0], acc[mi][0]);
        acc[mi][1] = MFMA16(a, bfr[1], acc[mi][1]);
      }
    }
    #pragma unroll
    for (int mi=0;mi<2;mi++){
      int mt = wave*2 + mi;
      float4 bb = *(const float4*)(b1v + mt*16 + quad*4);
      #pragma unroll
      for (int nt=0;nt<2;nt++){
        bf16x4 p;
        p[0]=(__bf16)fmaxf(acc[mi][nt][0]+bb.x,0.f);
        p[1]=(__bf16)fmaxf(acc[mi][nt][1]+bb.y,0.f);
        p[2]=(__bf16)fmaxf(acc[mi][nt][2]+bb.z,0.f);
        p[3]=(__bf16)fmaxf(acc[mi][nt][3]+bb.w,0.f);
        *(bf16x4*)(h2 + (nt*16 + l16)*HSTRIDE + mt*16 + quad*4) = p;
      }
    }
  }
  __syncthreads();

  // ---- GEMM3 (original): raw[b][n] = h2[b][:] @ Wout[:][n] + bout[n]
  // n-tiles 0..11 split {2,2,2,2,1,1,1,1}; both batch tiles per wave.
  {
    const int ncnt = (wave < 4) ? 2 : 1;
    const int nbase = (wave < 4) ? wave*2 : wave + 4;
    f32x4 acc[2][2];
    #pragma unroll
    for (int mi=0;mi<2;mi++){ acc[mi][0]=z4; acc[mi][1]=z4; }
    #pragma unroll
    for (int kb=0;kb<8;kb++){
      bf16x8 af[2];
      #pragma unroll
      for (int mi=0;mi<2;mi++)
        af[mi] = *(const bf16x8*)(h2 + (mi*16 + l16)*HSTRIDE + kb*32 + quad*8);
      #pragma unroll
      for (int ni=0;ni<2;ni++){
        if (ni < ncnt){
          bf16x8 b = *(const bf16x8*)(swWo + ((kb*12 + nbase + ni)*64 + lane)*8);
          acc[0][ni] = MFMA16(af[0], b, acc[0][ni]);
          acc[1][ni] = MFMA16(af[1], b, acc[1][ni]);
        }
      }
    }
    #pragma unroll
    for (int ni=0;ni<2;ni++){
      int col = (nbase + ni)*16 + l16;
      if (ni < ncnt && col < 184){
        int t = (col * 713) >> 14;     // col / 23
        float bias = boutv[col];
        #pragma unroll
        for (int mi=0;mi<2;mi++)
          #pragma unroll
          for (int r=0;r<4;r++){
            int row = mi*16 + quad*4 + r;
            rawb[row*HSTRIDE + col + t] = (__bf16)(acc[mi][ni][r] + bias);
          }
      }
    }
  }
  __syncthreads();

  // ---- RQ spline epilogue: 256 tasks on tid<256; tid>=256 does x2 passthrough
  if (tid < 256){
    int row = tid >> 3;
    int t   = tid & 7;
    long gr = row0 + row;
    float xv = x[gr*16 + t];

    const __bf16* rr = rawb + row*HSTRIDE + t*24;   // 48B slots: b128-aligned
    bf16x8 v0 = *(const bf16x8*)(rr);
    bf16x8 v1 = *(const bf16x8*)(rr + 8);
    bf16x8 v2 = *(const bf16x8*)(rr + 16);

    float ew[8], eh[8];
    float sw_ = 0.f, sh_ = 0.f;
    #pragma unroll
    for (int i=0;i<8;i++){ ew[i] = __expf((float)v0[i]); sw_ += ew[i]; }
    #pragma unroll
    for (int i=0;i<8;i++){ eh[i] = __expf((float)v1[i]); sh_ += eh[i]; }
    float cw = 1.9984f * __builtin_amdgcn_rcpf(sw_);
    float ch = 1.9984f * __builtin_amdgcn_rcpf(sh_);

    float d[9];
    d[0] = 1.f; d[8] = 1.f;
    #pragma unroll
    for (int i=0;i<7;i++){
      float z = (float)v2[i] + 0.54116666f;     // log(exp(1-MIN_D)-1)
      d[i+1] = fmaxf(z, 0.f) + __logf(1.f + __expf(-fabsf(z))) + 1e-4f;
    }

    bool msk = (xv <= -0.999f) || (xv >= 0.999f);
    float xin = msk ? 0.f : xv;

    float w_i = fmaf(ew[0], cw, 2e-4f);
    float h_i = fmaf(eh[0], ch, 2e-4f);
    float edge = -1.f + w_i, cy = -1.f + h_i;
    float xk = -1.f, yk = -1.f, wk = w_i, hk = h_i, dk = d[0], dk1 = d[1];
    #pragma unroll
    for (int i=1;i<8;i++){
      w_i = fmaf(ew[i], cw, 2e-4f);
      h_i = fmaf(eh[i], ch, 2e-4f);
      bool le = (edge <= xin);
      xk  = le ? edge : xk;
      yk  = le ? cy   : yk;
      wk  = le ? w_i  : wk;
      hk  = le ? h_i  : hk;
      dk  = le ? d[i] : dk;
      dk1 = le ? d[i+1] : dk1;
      edge += w_i; cy += h_i;
    }

    float rwk = __builtin_amdgcn_rcpf(wk);
    float sk  = hk * rwk;
    float eps = (xin - xk) * rwk;
    float om  = 1.f - eps;
    float et  = eps * om;
    float e2  = eps * eps;
    float beta  = sk + (dk1 + dk - 2.f*sk) * et;
    float rb    = __builtin_amdgcn_rcpf(beta);
    float alpha = hk * (sk*e2 + dk*et);
    float yv  = msk ? xv : (yk + alpha * rb);
    float num = dk1*e2 + 2.f*sk*et + dk*om*om;
    float arg = sk*sk*num*rb*rb;
    float ld  = msk ? 0.f : __logf(arg);

    out[gr*16 + t] = yv;
    ldet[tid] = ld;
  } else {
    int p   = tid - 256;
    long gr = row0 + (p >> 3);
    int t   = p & 7;
    out[gr*16 + 8 + t] = x[gr*16 + 8 + t];      // x2 passthrough
  }
  __syncthreads();

  if (tid < ROWS){
    float s = 0.f;
    #pragma unroll
    for (int t=0;t<8;t++) s += ldet[tid*8 + t];
    out[(long)nrows*16 + row0 + tid] = s;
  }
}

extern "C" void kernel_launch(void* const* d_in, const int* in_sizes, int n_in,
                              void* d_out, int out_size, void* d_ws, size_t ws_size,
                              hipStream_t stream)
{
  const float* x    = (const float*)d_in[0];
  const float* W0   = (const float*)d_in[1];
  const float* b0   = (const float*)d_in[2];
  const float* W1   = (const float*)d_in[3];
  const float* b1   = (const float*)d_in[4];
  const float* Wout = (const float*)d_in[5];
  const float* bout = (const float*)d_in[6];
  float* out = (float*)d_out;
  __bf16* sw = (__bf16*)d_ws;

  int nrows = in_sizes[0] / 16;          // 524288
  int ntiles = nrows / ROWS;             // 16384

  prep_kernel<<<(SW_TOTAL + 255)/256, 256, 0, stream>>>(W0, W1, Wout, sw);
  fused_kernel<<<ntiles, 512, 0, stream>>>(x, b0, b1, bout, sw, out, nrows);
}

// Round 5
// 248.031 us; speedup vs baseline: 1.1132x; 1.1132x over previous
//
#include <hip/hip_runtime.h>
#include <hip/hip_bf16.h>

// CouplingSplineLayer fused kernel for MI355X (gfx950), round 5.
// R5 = R3 skeleton (64 rows, 512 thr, 2 blocks/CU) + VALU-count reduction:
//  - spline: softplus only for the 2 selected derivs (sentinel-select raw z),
//    exp2-native softmax (Wout/bout pre-scaled by log2e in prep),
//    f32x2 packed scan (v_pk_fma/add_f32).
//  - GEMM epilogues: packed f32 add/max + packed bf16 cvt (v_cvt_pk_bf16_f32).
//  - x2 passthrough as float4 copies.
// Rationale: R2-R4 showed dur invariant (~220us) under DS-cut and 2x occupancy;
// VALUBusy ~50% is the only large invariant counter -> VALU-issue-count bound
// at ~50% issue efficiency. Cut VALU ops ~30%.

typedef __bf16 bf16x8 __attribute__((ext_vector_type(8)));
typedef __bf16 bf16x4v __attribute__((ext_vector_type(4)));
typedef float  f32x8 __attribute__((ext_vector_type(8)));
typedef float  f32x4 __attribute__((ext_vector_type(4)));
typedef float  f32x2 __attribute__((ext_vector_type(2)));

#define MFMA16(a,b,c) __builtin_amdgcn_mfma_f32_16x16x32_bf16((a),(b),(c),0,0,0)

#define SW_W1_OFF 8192      // W0: 1 kb * 16 tiles * 512
#define SW_WO_OFF 73728     // W1: 8 kb * 16 tiles * 512
#define SW_TOTAL  122880    // Wout: 8 kb * 12 tiles * 512

#define ROWS    64
#define HSTRIDE 264         // h row stride in bf16 (528 B: 16B-aligned)
#define LOG2E   1.44269504f
#define LN2     0.69314718f
#define SPCONST 0.7806568f      // log(exp(1-1e-4)-1) * log2e
#define ZSENT  (-0.00015680f)   // raw-z sentinel whose softplus-chain -> d = 1

__global__ void prep_kernel(const float* __restrict__ W0,
                            const float* __restrict__ W1,
                            const float* __restrict__ Wout,
                            __bf16* __restrict__ sw)
{
  int i = blockIdx.x * 256 + threadIdx.x;
  if (i >= SW_TOTAL) return;
  const float* src; int K, N, NT, li;
  float scale = 1.0f;
  if (i < SW_W1_OFF)      { src = W0;   K = 8;   N = 256; NT = 16; li = i; }
  else if (i < SW_WO_OFF) { src = W1;   K = 256; N = 256; NT = 16; li = i - SW_W1_OFF; }
  else { src = Wout; K = 256; N = 184; NT = 12; li = i - SW_WO_OFF; scale = LOG2E; }
  int j    = li & 7;
  int l    = (li >> 3) & 63;
  int rest = li >> 9;
  int nt   = rest % NT;
  int kb   = rest / NT;
  int k = kb * 32 + ((l >> 4) << 3) + j;
  int n = nt * 16 + (l & 15);
  float v = (k < K && n < N) ? src[k * N + n] * scale : 0.0f;
  sw[i] = (__bf16)v;
}

__device__ __forceinline__ bf16x4v relu_cvt4(f32x4 acc, float4 bb){
  f32x4 s;
  s[0] = acc[0] + bb.x; s[1] = acc[1] + bb.y;
  s[2] = acc[2] + bb.z; s[3] = acc[3] + bb.w;
  f32x4 z = {0.f, 0.f, 0.f, 0.f};
  s = __builtin_elementwise_max(s, z);
  return __builtin_convertvector(s, bf16x4v);   // v_cvt_pk_bf16_f32 x2
}

__global__ __launch_bounds__(512, 4)
void fused_kernel(const float* __restrict__ x,
                  const float* __restrict__ b0v,
                  const float* __restrict__ b1v,
                  const float* __restrict__ boutv,
                  const __bf16* __restrict__ sw,
                  float* __restrict__ out,
                  int nrows)
{
  // [0, 33792)      h1 (64 x HSTRIDE bf16), later aliased by raw
  // [33792, 67584)  h2 (64 x HSTRIDE bf16), later aliased by ldet (512 f32)
  __shared__ __align__(16) unsigned char smem[2 * ROWS * HSTRIDE * 2];
  __bf16* h1   = (__bf16*)smem;
  __bf16* h2   = (__bf16*)(smem + ROWS * HSTRIDE * 2);
  __bf16* rawb = h1;
  float*  ldet = (float*)h2;

  const int tid  = threadIdx.x;
  const int wave = tid >> 6;
  const int lane = tid & 63;
  const int quad = lane >> 4;
  const int l16  = lane & 15;
  const int row0 = blockIdx.x * ROWS;

  const __bf16* swW1 = sw + SW_W1_OFF;
  const __bf16* swWo = sw + SW_WO_OFF;
  const f32x4 z4 = {0.f, 0.f, 0.f, 0.f};

  // ---- x2 passthrough: 2 float4 per row on 128 threads (independent; issues early)
  if (tid < 2*ROWS){
    int r = tid >> 1, hf = tid & 1;
    long g = (long)row0 + r;
    *(float4*)(out + g*16 + 8 + hf*4) = *(const float4*)(x + g*16 + 8 + hf*4);
  }

  const int mq = wave >> 1;   // m-quarter (4 m-tiles each) for G1/G2
  const int nh = wave & 1;    // batch-tile pair for G1/G2

  // ---- GEMM1 (transposed): h1[b][m] = relu(sum_k W0[k][m]*x2[b][k] + b0[m])
  {
    bf16x8 bfr[2];
    #pragma unroll
    for (int nt = 0; nt < 2; nt++){
      bf16x8 b = {};                       // k=quad*8+j; only quad 0 (k<8) real
      if (quad == 0){
        const float* xp = x + (long)(row0 + (nh*2 + nt)*16 + l16)*16 + 8;
        float4 u = *(const float4*)xp;
        float4 v = *(const float4*)(xp + 4);
        f32x8 xf; xf[0]=u.x; xf[1]=u.y; xf[2]=u.z; xf[3]=u.w;
                  xf[4]=v.x; xf[5]=v.y; xf[6]=v.z; xf[7]=v.w;
        b = __builtin_convertvector(xf, bf16x8);
      }
      bfr[nt] = b;
    }
    #pragma unroll
    for (int mi = 0; mi < 4; mi++){
      int mt = mq*4 + mi;
      bf16x8 a = *(const bf16x8*)(sw + (mt*64 + lane)*8);
      f32x4 acc0 = MFMA16(a, bfr[0], z4);
      f32x4 acc1 = MFMA16(a, bfr[1], z4);
      float4 bb = *(const float4*)(b0v + mt*16 + quad*4);
      *(bf16x4v*)(h1 + ((nh*2+0)*16 + l16)*HSTRIDE + mt*16 + quad*4) = relu_cvt4(acc0, bb);
      *(bf16x4v*)(h1 + ((nh*2+1)*16 + l16)*HSTRIDE + mt*16 + quad*4) = relu_cvt4(acc1, bb);
    }
  }
  __syncthreads();

  // ---- GEMM2 (transposed): h2[b][m] = relu(sum_k W1[k][m]*h1[b][k] + b1[m])
  {
    f32x4 acc[4][2];
    #pragma unroll
    for (int mi=0;mi<4;mi++){ acc[mi][0]=z4; acc[mi][1]=z4; }
    #pragma unroll
    for (int kb=0;kb<8;kb++){
      bf16x8 bfr[2];
      #pragma unroll
      for (int nt=0;nt<2;nt++)
        bfr[nt] = *(const bf16x8*)(h1 + ((nh*2+nt)*16 + l16)*HSTRIDE + kb*32 + quad*8);
      #pragma unroll
      for (int mi=0;mi<4;mi++){
        bf16x8 a = *(const bf16x8*)(swW1 + ((kb*16 + mq*4 + mi)*64 + lane)*8);
        acc[mi][0] = MFMA16(a, bfr[0], acc[mi][0]);
        acc[mi][1] = MFMA16(a, bfr[1], acc[mi][1]);
      }
    }
    #pragma unroll
    for (int mi=0;mi<4;mi++){
      int mt = mq*4 + mi;
      float4 bb = *(const float4*)(b1v + mt*16 + quad*4);
      #pragma unroll
      for (int nt=0;nt<2;nt++)
        *(bf16x4v*)(h2 + ((nh*2+nt)*16 + l16)*HSTRIDE + mt*16 + quad*4) = relu_cvt4(acc[mi][nt], bb);
    }
  }
  __syncthreads();

  // ---- GEMM3 (original): raw2 = h2 @ Wout_s + bout*log2e (into spline LDS slots)
  {
    const int mh = wave >> 2;          // batch-half (2 m-tiles each)
    const int nc = wave & 3;           // 3 n-tiles each
    f32x4 acc[2][3];
    #pragma unroll
    for (int mi=0;mi<2;mi++)
      #pragma unroll
      for (int ni=0;ni<3;ni++) acc[mi][ni] = z4;
    #pragma unroll
    for (int kb=0;kb<8;kb++){
      bf16x8 af[2];
      #pragma unroll
      for (int mi=0;mi<2;mi++)
        af[mi] = *(const bf16x8*)(h2 + ((mh*2+mi)*16 + l16)*HSTRIDE + kb*32 + quad*8);
      #pragma unroll
      for (int ni=0;ni<3;ni++){
        bf16x8 b = *(const bf16x8*)(swWo + ((kb*12 + nc*3 + ni)*64 + lane)*8);
        acc[0][ni] = MFMA16(af[0], b, acc[0][ni]);
        acc[1][ni] = MFMA16(af[1], b, acc[1][ni]);
      }
    }
    #pragma unroll
    for (int ni=0;ni<3;ni++){
      int col = (nc*3 + ni)*16 + l16;
      if (col < 184){
        int t = (col * 713) >> 14;     // col / 23
        float bias = boutv[col] * LOG2E;
        #pragma unroll
        for (int mi=0;mi<2;mi++)
          #pragma unroll
          for (int r=0;r<4;r++){
            int row = (mh*2+mi)*16 + quad*4 + r;
            rawb[row*HSTRIDE + col + t] = (__bf16)(acc[mi][ni][r] + bias);
          }
      }
    }
  }
  __syncthreads();

  // ---- RQ spline epilogue: 512 tasks, 1/thread
  {
    int row = tid >> 3;
    int t   = tid & 7;
    long gr = row0 + row;
    float xv = x[gr*16 + t];

    const __bf16* rr = rawb + row*HSTRIDE + t*24;   // 48B slots, b128-aligned
    bf16x8 v0 = *(const bf16x8*)(rr);
    bf16x8 v1 = *(const bf16x8*)(rr + 8);
    bf16x8 v2 = *(const bf16x8*)(rr + 16);

    // raw2 already in log2-units: 2^raw2 = e^raw exactly
    f32x2 ewh[8];
    f32x2 sum = {0.f, 0.f};
    #pragma unroll
    for (int i=0;i<8;i++){
      f32x2 e;
      e[0] = __builtin_amdgcn_exp2f((float)v0[i]);
      e[1] = __builtin_amdgcn_exp2f((float)v1[i]);
      ewh[i] = e; sum += e;
    }
    f32x2 scale;
    scale[0] = 1.9984f * __builtin_amdgcn_rcpf(sum[0]);
    scale[1] = 1.9984f * __builtin_amdgcn_rcpf(sum[1]);
    const f32x2 off2 = {2e-4f, 2e-4f};

    bool msk = (xv <= -0.999f) || (xv >= 0.999f);
    float xin = msk ? 0.f : xv;

    // packed scan: (w,h) pairs, (edge,cy) pairs; sentinel-select raw z for d's
    f32x2 whi = ewh[0]*scale + off2;
    f32x2 ec; ec[0] = -1.f + whi[0]; ec[1] = -1.f + whi[1];
    f32x2 xyk = {-1.f, -1.f};
    f32x2 whk = whi;
    float zk = ZSENT, zk1 = (float)v2[0];
    #pragma unroll
    for (int i=1;i<8;i++){
      whi = ewh[i]*scale + off2;
      bool le = (ec[0] <= xin);
      xyk = le ? ec : xyk;
      whk = le ? whi : whk;
      zk  = le ? (float)v2[i-1] : zk;
      zk1 = le ? ((i==7) ? ZSENT : (float)v2[i]) : zk1;
      ec += whi;
    }

    // softplus (base-2) only for the two selected derivatives
    float za = zk + SPCONST, zb = zk1 + SPCONST;
    float dk  = (fmaxf(za,0.f) + __builtin_amdgcn_logf(1.f + __builtin_amdgcn_exp2f(-fabsf(za))))*LN2 + 1e-4f;
    float dk1 = (fmaxf(zb,0.f) + __builtin_amdgcn_logf(1.f + __builtin_amdgcn_exp2f(-fabsf(zb))))*LN2 + 1e-4f;

    float rwk = __builtin_amdgcn_rcpf(whk[0]);
    float sk  = whk[1] * rwk;
    float eps = (xin - xyk[0]) * rwk;
    float om  = 1.f - eps;
    float et  = eps * om;
    float e2  = eps * eps;
    float beta  = sk + (dk1 + dk - 2.f*sk) * et;
    float rb    = __builtin_amdgcn_rcpf(beta);
    float alpha = whk[1] * (sk*e2 + dk*et);
    float yv  = msk ? xv : (xyk[1] + alpha * rb);
    float num = dk1*e2 + 2.f*sk*et + dk*om*om;
    float ld  = msk ? 0.f : __builtin_amdgcn_logf(sk*sk*num*rb*rb) * LN2;

    out[gr*16 + t] = yv;
    ldet[tid] = ld;
  }
  __syncthreads();

  if (tid < ROWS){
    float s = 0.f;
    #pragma unroll
    for (int t=0;t<8;t++) s += ldet[tid*8 + t];
    out[(long)nrows*16 + row0 + tid] = s;
  }
}

extern "C" void kernel_launch(void* const* d_in, const int* in_sizes, int n_in,
                              void* d_out, int out_size, void* d_ws, size_t ws_size,
                              hipStream_t stream)
{
  const float* x    = (const float*)d_in[0];
  const float* W0   = (const float*)d_in[1];
  const float* b0   = (const float*)d_in[2];
  const float* W1   = (const float*)d_in[3];
  const float* b1   = (const float*)d_in[4];
  const float* Wout = (const float*)d_in[5];
  const float* bout = (const float*)d_in[6];
  float* out = (float*)d_out;
  __bf16* sw = (__bf16*)d_ws;

  int nrows = in_sizes[0] / 16;          // 524288
  int ntiles = nrows / ROWS;             // 8192

  prep_kernel<<<(SW_TOTAL + 255)/256, 256, 0, stream>>>(W0, W1, Wout, sw);
  fused_kernel<<<ntiles, 512, 0, stream>>>(x, b0, b1, bout, sw, out, nrows);
}

// Round 6
// 243.535 us; speedup vs baseline: 1.1338x; 1.0185x over previous
//
#include <hip/hip_runtime.h>
#include <hip/hip_bf16.h>

// CouplingSplineLayer fused kernel for MI355X (gfx950), round 6.
// R6 = R5 math + single aliased LDS buffer (h1/h2/raw share one 33.8 KB
// region; accumulators held in registers across each k-loop, written back
// after a barrier) -> LDS 67.6 -> 35.8 KB -> 4 blocks/CU = 32 waves/CU
// (100% occupancy cap) while keeping the full-width 512-task epilogue and
// once-per-block weight reads. Tests the latency/barrier-overlap theory
// cleanly (R4's attempt had a half-width epilogue confound).

typedef __bf16 bf16x8 __attribute__((ext_vector_type(8)));
typedef __bf16 bf16x4v __attribute__((ext_vector_type(4)));
typedef float  f32x8 __attribute__((ext_vector_type(8)));
typedef float  f32x4 __attribute__((ext_vector_type(4)));
typedef float  f32x2 __attribute__((ext_vector_type(2)));

#define MFMA16(a,b,c) __builtin_amdgcn_mfma_f32_16x16x32_bf16((a),(b),(c),0,0,0)

#define SW_W1_OFF 8192      // W0: 1 kb * 16 tiles * 512
#define SW_WO_OFF 73728     // W1: 8 kb * 16 tiles * 512
#define SW_TOTAL  122880    // Wout: 8 kb * 12 tiles * 512

#define ROWS    64
#define HSTRIDE 264         // h row stride in bf16 (528 B: 16B-aligned)
#define LOG2E   1.44269504f
#define LN2     0.69314718f
#define SPCONST 0.7806568f      // log(exp(1-1e-4)-1) * log2e
#define ZSENT  (-0.00015680f)   // raw-z sentinel whose softplus-chain -> d = 1

__global__ void prep_kernel(const float* __restrict__ W0,
                            const float* __restrict__ W1,
                            const float* __restrict__ Wout,
                            __bf16* __restrict__ sw)
{
  int i = blockIdx.x * 256 + threadIdx.x;
  if (i >= SW_TOTAL) return;
  const float* src; int K, N, NT, li;
  float scale = 1.0f;
  if (i < SW_W1_OFF)      { src = W0;   K = 8;   N = 256; NT = 16; li = i; }
  else if (i < SW_WO_OFF) { src = W1;   K = 256; N = 256; NT = 16; li = i - SW_W1_OFF; }
  else { src = Wout; K = 256; N = 184; NT = 12; li = i - SW_WO_OFF; scale = LOG2E; }
  int j    = li & 7;
  int l    = (li >> 3) & 63;
  int rest = li >> 9;
  int nt   = rest % NT;
  int kb   = rest / NT;
  int k = kb * 32 + ((l >> 4) << 3) + j;
  int n = nt * 16 + (l & 15);
  float v = (k < K && n < N) ? src[k * N + n] * scale : 0.0f;
  sw[i] = (__bf16)v;
}

__device__ __forceinline__ bf16x4v relu_cvt4(f32x4 acc, float4 bb){
  f32x4 s;
  s[0] = acc[0] + bb.x; s[1] = acc[1] + bb.y;
  s[2] = acc[2] + bb.z; s[3] = acc[3] + bb.w;
  f32x4 z = {0.f, 0.f, 0.f, 0.f};
  s = __builtin_elementwise_max(s, z);
  return __builtin_convertvector(s, bf16x4v);   // v_cvt_pk_bf16_f32 x2
}

__global__ __launch_bounds__(512, 4)
void fused_kernel(const float* __restrict__ x,
                  const float* __restrict__ b0v,
                  const float* __restrict__ b1v,
                  const float* __restrict__ boutv,
                  const __bf16* __restrict__ sw,
                  float* __restrict__ out,
                  int nrows)
{
  // ONE aliased buffer: h1, then h2 (in-place), then raw. ldet separate.
  __shared__ __align__(16) unsigned char smem[ROWS * HSTRIDE * 2];
  __shared__ __align__(16) float ldet[512];
  __bf16* hbuf = (__bf16*)smem;
  __bf16* rawb = hbuf;

  const int tid  = threadIdx.x;
  const int wave = tid >> 6;
  const int lane = tid & 63;
  const int quad = lane >> 4;
  const int l16  = lane & 15;
  const int row0 = blockIdx.x * ROWS;

  const __bf16* swW1 = sw + SW_W1_OFF;
  const __bf16* swWo = sw + SW_WO_OFF;
  const f32x4 z4 = {0.f, 0.f, 0.f, 0.f};

  // ---- x2 passthrough: 2 float4 per row on 128 threads (independent)
  if (tid < 2*ROWS){
    int r = tid >> 1, hf = tid & 1;
    long g = (long)row0 + r;
    *(float4*)(out + g*16 + 8 + hf*4) = *(const float4*)(x + g*16 + 8 + hf*4);
  }

  const int mq = wave >> 1;   // m-quarter (4 m-tiles each) for G1/G2
  const int nh = wave & 1;    // batch-tile pair for G1/G2

  // ---- GEMM1 (transposed): h1[b][m] = relu(sum_k W0[k][m]*x2[b][k] + b0[m])
  {
    bf16x8 bfr[2];
    #pragma unroll
    for (int nt = 0; nt < 2; nt++){
      bf16x8 b = {};                       // k=quad*8+j; only quad 0 (k<8) real
      if (quad == 0){
        const float* xp = x + (long)(row0 + (nh*2 + nt)*16 + l16)*16 + 8;
        float4 u = *(const float4*)xp;
        float4 v = *(const float4*)(xp + 4);
        f32x8 xf; xf[0]=u.x; xf[1]=u.y; xf[2]=u.z; xf[3]=u.w;
                  xf[4]=v.x; xf[5]=v.y; xf[6]=v.z; xf[7]=v.w;
        b = __builtin_convertvector(xf, bf16x8);
      }
      bfr[nt] = b;
    }
    #pragma unroll
    for (int mi = 0; mi < 4; mi++){
      int mt = mq*4 + mi;
      bf16x8 a = *(const bf16x8*)(sw + (mt*64 + lane)*8);
      f32x4 acc0 = MFMA16(a, bfr[0], z4);
      f32x4 acc1 = MFMA16(a, bfr[1], z4);
      float4 bb = *(const float4*)(b0v + mt*16 + quad*4);
      *(bf16x4v*)(hbuf + ((nh*2+0)*16 + l16)*HSTRIDE + mt*16 + quad*4) = relu_cvt4(acc0, bb);
      *(bf16x4v*)(hbuf + ((nh*2+1)*16 + l16)*HSTRIDE + mt*16 + quad*4) = relu_cvt4(acc1, bb);
    }
  }
  __syncthreads();

  // ---- GEMM2 (transposed): h2[b][m] = relu(sum_k W1[k][m]*h1[b][k] + b1[m])
  // accumulate in regs over all k (reads of h1 complete) -> barrier -> write in place
  {
    f32x4 acc[4][2];
    #pragma unroll
    for (int mi=0;mi<4;mi++){ acc[mi][0]=z4; acc[mi][1]=z4; }
    #pragma unroll
    for (int kb=0;kb<8;kb++){
      bf16x8 bfr[2];
      #pragma unroll
      for (int nt=0;nt<2;nt++)
        bfr[nt] = *(const bf16x8*)(hbuf + ((nh*2+nt)*16 + l16)*HSTRIDE + kb*32 + quad*8);
      #pragma unroll
      for (int mi=0;mi<4;mi++){
        bf16x8 a = *(const bf16x8*)(swW1 + ((kb*16 + mq*4 + mi)*64 + lane)*8);
        acc[mi][0] = MFMA16(a, bfr[0], acc[mi][0]);
        acc[mi][1] = MFMA16(a, bfr[1], acc[mi][1]);
      }
    }
    __syncthreads();
    #pragma unroll
    for (int mi=0;mi<4;mi++){
      int mt = mq*4 + mi;
      float4 bb = *(const float4*)(b1v + mt*16 + quad*4);
      #pragma unroll
      for (int nt=0;nt<2;nt++)
        *(bf16x4v*)(hbuf + ((nh*2+nt)*16 + l16)*HSTRIDE + mt*16 + quad*4) = relu_cvt4(acc[mi][nt], bb);
    }
  }
  __syncthreads();

  // ---- GEMM3 (original): raw2 = h2 @ Wout_s + bout*log2e
  // accumulate in regs -> barrier -> write raw in place
  {
    const int mh = wave >> 2;          // batch-half (2 m-tiles each)
    const int nc = wave & 3;           // 3 n-tiles each
    f32x4 acc[2][3];
    #pragma unroll
    for (int mi=0;mi<2;mi++)
      #pragma unroll
      for (int ni=0;ni<3;ni++) acc[mi][ni] = z4;
    #pragma unroll
    for (int kb=0;kb<8;kb++){
      bf16x8 af[2];
      #pragma unroll
      for (int mi=0;mi<2;mi++)
        af[mi] = *(const bf16x8*)(hbuf + ((mh*2+mi)*16 + l16)*HSTRIDE + kb*32 + quad*8);
      #pragma unroll
      for (int ni=0;ni<3;ni++){
        bf16x8 b = *(const bf16x8*)(swWo + ((kb*12 + nc*3 + ni)*64 + lane)*8);
        acc[0][ni] = MFMA16(af[0], b, acc[0][ni]);
        acc[1][ni] = MFMA16(af[1], b, acc[1][ni]);
      }
    }
    __syncthreads();
    #pragma unroll
    for (int ni=0;ni<3;ni++){
      int col = (nc*3 + ni)*16 + l16;
      if (col < 184){
        int t = (col * 713) >> 14;     // col / 23
        float bias = boutv[col] * LOG2E;
        #pragma unroll
        for (int mi=0;mi<2;mi++)
          #pragma unroll
          for (int r=0;r<4;r++){
            int row = (mh*2+mi)*16 + quad*4 + r;
            rawb[row*HSTRIDE + col + t] = (__bf16)(acc[mi][ni][r] + bias);
          }
      }
    }
  }
  __syncthreads();

  // ---- RQ spline epilogue: 512 tasks, 1/thread
  {
    int row = tid >> 3;
    int t   = tid & 7;
    long gr = row0 + row;
    float xv = x[gr*16 + t];

    const __bf16* rr = rawb + row*HSTRIDE + t*24;   // 48B slots, b128-aligned
    bf16x8 v0 = *(const bf16x8*)(rr);
    bf16x8 v1 = *(const bf16x8*)(rr + 8);
    bf16x8 v2 = *(const bf16x8*)(rr + 16);

    // raw2 already in log2-units: 2^raw2 = e^raw exactly
    f32x2 ewh[8];
    f32x2 sum = {0.f, 0.f};
    #pragma unroll
    for (int i=0;i<8;i++){
      f32x2 e;
      e[0] = __builtin_amdgcn_exp2f((float)v0[i]);
      e[1] = __builtin_amdgcn_exp2f((float)v1[i]);
      ewh[i] = e; sum += e;
    }
    f32x2 scale;
    scale[0] = 1.9984f * __builtin_amdgcn_rcpf(sum[0]);
    scale[1] = 1.9984f * __builtin_amdgcn_rcpf(sum[1]);
    const f32x2 off2 = {2e-4f, 2e-4f};

    bool msk = (xv <= -0.999f) || (xv >= 0.999f);
    float xin = msk ? 0.f : xv;

    // packed scan; sentinel-select raw z for the two needed derivatives
    f32x2 whi = ewh[0]*scale + off2;
    f32x2 ec; ec[0] = -1.f + whi[0]; ec[1] = -1.f + whi[1];
    f32x2 xyk = {-1.f, -1.f};
    f32x2 whk = whi;
    float zk = ZSENT, zk1 = (float)v2[0];
    #pragma unroll
    for (int i=1;i<8;i++){
      whi = ewh[i]*scale + off2;
      bool le = (ec[0] <= xin);
      xyk = le ? ec : xyk;
      whk = le ? whi : whk;
      zk  = le ? (float)v2[i-1] : zk;
      zk1 = le ? ((i==7) ? ZSENT : (float)v2[i]) : zk1;
      ec += whi;
    }

    // softplus (base-2) only for the two selected derivatives
    float za = zk + SPCONST, zb = zk1 + SPCONST;
    float dk  = (fmaxf(za,0.f) + __builtin_amdgcn_logf(1.f + __builtin_amdgcn_exp2f(-fabsf(za))))*LN2 + 1e-4f;
    float dk1 = (fmaxf(zb,0.f) + __builtin_amdgcn_logf(1.f + __builtin_amdgcn_exp2f(-fabsf(zb))))*LN2 + 1e-4f;

    float rwk = __builtin_amdgcn_rcpf(whk[0]);
    float sk  = whk[1] * rwk;
    float eps = (xin - xyk[0]) * rwk;
    float om  = 1.f - eps;
    float et  = eps * om;
    float e2  = eps * eps;
    float beta  = sk + (dk1 + dk - 2.f*sk) * et;
    float rb    = __builtin_amdgcn_rcpf(beta);
    float alpha = whk[1] * (sk*e2 + dk*et);
    float yv  = msk ? xv : (xyk[1] + alpha * rb);
    float num = dk1*e2 + 2.f*sk*et + dk*om*om;
    float ld  = msk ? 0.f : __builtin_amdgcn_logf(sk*sk*num*rb*rb) * LN2;

    out[gr*16 + t] = yv;
    ldet[tid] = ld;
  }
  __syncthreads();

  if (tid < ROWS){
    float s = 0.f;
    #pragma unroll
    for (int t=0;t<8;t++) s += ldet[tid*8 + t];
    out[(long)nrows*16 + row0 + tid] = s;
  }
}

extern "C" void kernel_launch(void* const* d_in, const int* in_sizes, int n_in,
                              void* d_out, int out_size, void* d_ws, size_t ws_size,
                              hipStream_t stream)
{
  const float* x    = (const float*)d_in[0];
  const float* W0   = (const float*)d_in[1];
  const float* b0   = (const float*)d_in[2];
  const float* W1   = (const float*)d_in[3];
  const float* b1   = (const float*)d_in[4];
  const float* Wout = (const float*)d_in[5];
  const float* bout = (const float*)d_in[6];
  float* out = (float*)d_out;
  __bf16* sw = (__bf16*)d_ws;

  int nrows = in_sizes[0] / 16;          // 524288
  int ntiles = nrows / ROWS;             // 8192

  prep_kernel<<<(SW_TOTAL + 255)/256, 256, 0, stream>>>(W0, W1, Wout, sw);
  fused_kernel<<<ntiles, 512, 0, stream>>>(x, b0, b1, bout, sw, out, nrows);
}

// Round 7
// 227.439 us; speedup vs baseline: 1.2140x; 1.0708x over previous
//
#include <hip/hip_runtime.h>
#include <hip/hip_bf16.h>

// CouplingSplineLayer fused kernel for MI355X (gfx950), round 7.
// R7 = R6 math + ROWS=128 per block (512 thr): each wave holds 4 batch-tiles
// in registers, so W1/Wout stream from L2 once per 128 rows instead of per 64
// -> weight vmem traffic (the dominant pipe, ~107us in R6's budget) halves.
// ldet reduction via __shfl_xor (8 t-lanes are adjacent) - no LDS, no barrier.
// LDS = one aliased 66KB h-buffer -> 2 blocks/CU.

typedef __bf16 bf16x8 __attribute__((ext_vector_type(8)));
typedef __bf16 bf16x4v __attribute__((ext_vector_type(4)));
typedef float  f32x8 __attribute__((ext_vector_type(8)));
typedef float  f32x4 __attribute__((ext_vector_type(4)));
typedef float  f32x2 __attribute__((ext_vector_type(2)));

#define MFMA16(a,b,c) __builtin_amdgcn_mfma_f32_16x16x32_bf16((a),(b),(c),0,0,0)

#define SW_W1_OFF 8192      // W0: 1 kb * 16 tiles * 512
#define SW_WO_OFF 73728     // W1: 8 kb * 16 tiles * 512
#define SW_TOTAL  122880    // Wout: 8 kb * 12 tiles * 512

#define ROWS    128
#define HSTRIDE 264         // h row stride in bf16 (528 B: 16B-aligned)
#define LOG2E   1.44269504f
#define LN2     0.69314718f
#define SPCONST 0.7806568f      // log(exp(1-1e-4)-1) * log2e
#define ZSENT  (-0.00015680f)   // raw-z sentinel whose softplus-chain -> d = 1

__global__ void prep_kernel(const float* __restrict__ W0,
                            const float* __restrict__ W1,
                            const float* __restrict__ Wout,
                            __bf16* __restrict__ sw)
{
  int i = blockIdx.x * 256 + threadIdx.x;
  if (i >= SW_TOTAL) return;
  const float* src; int K, N, NT, li;
  float scale = 1.0f;
  if (i < SW_W1_OFF)      { src = W0;   K = 8;   N = 256; NT = 16; li = i; }
  else if (i < SW_WO_OFF) { src = W1;   K = 256; N = 256; NT = 16; li = i - SW_W1_OFF; }
  else { src = Wout; K = 256; N = 184; NT = 12; li = i - SW_WO_OFF; scale = LOG2E; }
  int j    = li & 7;
  int l    = (li >> 3) & 63;
  int rest = li >> 9;
  int nt   = rest % NT;
  int kb   = rest / NT;
  int k = kb * 32 + ((l >> 4) << 3) + j;
  int n = nt * 16 + (l & 15);
  float v = (k < K && n < N) ? src[k * N + n] * scale : 0.0f;
  sw[i] = (__bf16)v;
}

__device__ __forceinline__ bf16x4v relu_cvt4(f32x4 acc, float4 bb){
  f32x4 s;
  s[0] = acc[0] + bb.x; s[1] = acc[1] + bb.y;
  s[2] = acc[2] + bb.z; s[3] = acc[3] + bb.w;
  f32x4 z = {0.f, 0.f, 0.f, 0.f};
  s = __builtin_elementwise_max(s, z);
  return __builtin_convertvector(s, bf16x4v);   // v_cvt_pk_bf16_f32 x2
}

__global__ __launch_bounds__(512, 4)
void fused_kernel(const float* __restrict__ x,
                  const float* __restrict__ b0v,
                  const float* __restrict__ b1v,
                  const float* __restrict__ boutv,
                  const __bf16* __restrict__ sw,
                  float* __restrict__ out,
                  int nrows)
{
  // ONE aliased buffer: h1 -> h2 (in place) -> raw. 128 x 264 bf16 = 66 KB.
  __shared__ __align__(16) unsigned char smem[ROWS * HSTRIDE * 2];
  __bf16* hbuf = (__bf16*)smem;
  __bf16* rawb = hbuf;

  const int tid  = threadIdx.x;
  const int wave = tid >> 6;
  const int lane = tid & 63;
  const int quad = lane >> 4;
  const int l16  = lane & 15;
  const int row0 = blockIdx.x * ROWS;

  const __bf16* swW1 = sw + SW_W1_OFF;
  const __bf16* swWo = sw + SW_WO_OFF;
  const f32x4 z4 = {0.f, 0.f, 0.f, 0.f};

  // ---- x2 passthrough: 2 float4 per row on 256 threads (independent)
  if (tid < 2*ROWS){
    int r = tid >> 1, hf = tid & 1;
    long g = (long)row0 + r;
    *(float4*)(out + g*16 + 8 + hf*4) = *(const float4*)(x + g*16 + 8 + hf*4);
  }

  const int mq = wave >> 1;   // m-quarter (4 m-tiles) for G1/G2
  const int nh = wave & 1;    // batch-half (4 batch-tiles) for G1/G2

  // ---- GEMM1 (transposed): h1[b][m] = relu(sum_k W0[k][m]*x2[b][k] + b0[m])
  {
    bf16x8 bfr[4];
    #pragma unroll
    for (int nt = 0; nt < 4; nt++){
      bf16x8 b = {};                       // k=quad*8+j; only quad 0 (k<8) real
      if (quad == 0){
        const float* xp = x + (long)(row0 + (nh*4 + nt)*16 + l16)*16 + 8;
        float4 u = *(const float4*)xp;
        float4 v = *(const float4*)(xp + 4);
        f32x8 xf; xf[0]=u.x; xf[1]=u.y; xf[2]=u.z; xf[3]=u.w;
                  xf[4]=v.x; xf[5]=v.y; xf[6]=v.z; xf[7]=v.w;
        b = __builtin_convertvector(xf, bf16x8);
      }
      bfr[nt] = b;
    }
    #pragma unroll
    for (int mi = 0; mi < 4; mi++){
      int mt = mq*4 + mi;
      bf16x8 a = *(const bf16x8*)(sw + (mt*64 + lane)*8);
      float4 bb = *(const float4*)(b0v + mt*16 + quad*4);
      #pragma unroll
      for (int nt = 0; nt < 4; nt++){
        f32x4 acc = MFMA16(a, bfr[nt], z4);
        *(bf16x4v*)(hbuf + ((nh*4+nt)*16 + l16)*HSTRIDE + mt*16 + quad*4) = relu_cvt4(acc, bb);
      }
    }
  }
  __syncthreads();

  // ---- GEMM2 (transposed): h2[b][m] = relu(sum_k W1[k][m]*h1[b][k] + b1[m])
  // wave = (mq quarter of m) x (nh half of batch: 4 tiles in registers)
  {
    f32x4 acc[4][4];                       // [mi][bt]
    #pragma unroll
    for (int mi=0;mi<4;mi++)
      #pragma unroll
      for (int bt=0;bt<4;bt++) acc[mi][bt] = z4;
    #pragma unroll
    for (int kb=0;kb<8;kb++){
      bf16x8 hf[4];
      #pragma unroll
      for (int bt=0;bt<4;bt++)
        hf[bt] = *(const bf16x8*)(hbuf + ((nh*4+bt)*16 + l16)*HSTRIDE + kb*32 + quad*8);
      #pragma unroll
      for (int mi=0;mi<4;mi++){
        bf16x8 a = *(const bf16x8*)(swW1 + ((kb*16 + mq*4 + mi)*64 + lane)*8);
        #pragma unroll
        for (int bt=0;bt<4;bt++)
          acc[mi][bt] = MFMA16(a, hf[bt], acc[mi][bt]);
      }
    }
    __syncthreads();
    #pragma unroll
    for (int mi=0;mi<4;mi++){
      int mt = mq*4 + mi;
      float4 bb = *(const float4*)(b1v + mt*16 + quad*4);
      #pragma unroll
      for (int bt=0;bt<4;bt++)
        *(bf16x4v*)(hbuf + ((nh*4+bt)*16 + l16)*HSTRIDE + mt*16 + quad*4) = relu_cvt4(acc[mi][bt], bb);
    }
  }
  __syncthreads();

  // ---- GEMM3 (original): raw2 = h2 @ Wout_s + bout*log2e
  // wave = (nc: 3 n-tiles) x (mh half of batch: 4 tiles in registers)
  {
    const int nc = wave & 3;
    const int mh = wave >> 2;
    f32x4 acc[4][3];                       // [bt][ni]
    #pragma unroll
    for (int bt=0;bt<4;bt++)
      #pragma unroll
      for (int ni=0;ni<3;ni++) acc[bt][ni] = z4;
    #pragma unroll
    for (int kb=0;kb<8;kb++){
      bf16x8 hf[4];
      #pragma unroll
      for (int bt=0;bt<4;bt++)
        hf[bt] = *(const bf16x8*)(hbuf + ((mh*4+bt)*16 + l16)*HSTRIDE + kb*32 + quad*8);
      #pragma unroll
      for (int ni=0;ni<3;ni++){
        bf16x8 b = *(const bf16x8*)(swWo + ((kb*12 + nc*3 + ni)*64 + lane)*8);
        #pragma unroll
        for (int bt=0;bt<4;bt++)
          acc[bt][ni] = MFMA16(hf[bt], b, acc[bt][ni]);
      }
    }
    __syncthreads();
    #pragma unroll
    for (int ni=0;ni<3;ni++){
      int col = (nc*3 + ni)*16 + l16;
      if (col < 184){
        int t = (col * 713) >> 14;     // col / 23
        float bias = boutv[col] * LOG2E;
        #pragma unroll
        for (int bt=0;bt<4;bt++)
          #pragma unroll
          for (int r=0;r<4;r++){
            int row = (mh*4+bt)*16 + quad*4 + r;
            rawb[row*HSTRIDE + col + t] = (__bf16)(acc[bt][ni][r] + bias);
          }
      }
    }
  }
  __syncthreads();

  // ---- RQ spline epilogue: 1024 tasks, 2/thread; ldet via shfl_xor
  float ldv[2];
  #pragma unroll
  for (int pp = 0; pp < 2; pp++){
    int p   = tid + pp*512;
    int row = p >> 3;
    int t   = p & 7;
    long gr = row0 + row;
    float xv = x[gr*16 + t];

    const __bf16* rr = rawb + row*HSTRIDE + t*24;   // 48B slots, b128-aligned
    bf16x8 v0 = *(const bf16x8*)(rr);
    bf16x8 v1 = *(const bf16x8*)(rr + 8);
    bf16x8 v2 = *(const bf16x8*)(rr + 16);

    // raw2 already in log2-units: 2^raw2 = e^raw exactly
    f32x2 ewh[8];
    f32x2 sum = {0.f, 0.f};
    #pragma unroll
    for (int i=0;i<8;i++){
      f32x2 e;
      e[0] = __builtin_amdgcn_exp2f((float)v0[i]);
      e[1] = __builtin_amdgcn_exp2f((float)v1[i]);
      ewh[i] = e; sum += e;
    }
    f32x2 scale;
    scale[0] = 1.9984f * __builtin_amdgcn_rcpf(sum[0]);
    scale[1] = 1.9984f * __builtin_amdgcn_rcpf(sum[1]);
    const f32x2 off2 = {2e-4f, 2e-4f};

    bool msk = (xv <= -0.999f) || (xv >= 0.999f);
    float xin = msk ? 0.f : xv;

    // packed scan; sentinel-select raw z for the two needed derivatives
    f32x2 whi = ewh[0]*scale + off2;
    f32x2 ec; ec[0] = -1.f + whi[0]; ec[1] = -1.f + whi[1];
    f32x2 xyk = {-1.f, -1.f};
    f32x2 whk = whi;
    float zk = ZSENT, zk1 = (float)v2[0];
    #pragma unroll
    for (int i=1;i<8;i++){
      whi = ewh[i]*scale + off2;
      bool le = (ec[0] <= xin);
      xyk = le ? ec : xyk;
      whk = le ? whi : whk;
      zk  = le ? (float)v2[i-1] : zk;
      zk1 = le ? ((i==7) ? ZSENT : (float)v2[i]) : zk1;
      ec += whi;
    }

    // softplus (base-2) only for the two selected derivatives
    float za = zk + SPCONST, zb = zk1 + SPCONST;
    float dk  = (fmaxf(za,0.f) + __builtin_amdgcn_logf(1.f + __builtin_amdgcn_exp2f(-fabsf(za))))*LN2 + 1e-4f;
    float dk1 = (fmaxf(zb,0.f) + __builtin_amdgcn_logf(1.f + __builtin_amdgcn_exp2f(-fabsf(zb))))*LN2 + 1e-4f;

    float rwk = __builtin_amdgcn_rcpf(whk[0]);
    float sk  = whk[1] * rwk;
    float eps = (xin - xyk[0]) * rwk;
    float om  = 1.f - eps;
    float et  = eps * om;
    float e2  = eps * eps;
    float beta  = sk + (dk1 + dk - 2.f*sk) * et;
    float rb    = __builtin_amdgcn_rcpf(beta);
    float alpha = whk[1] * (sk*e2 + dk*et);
    float yv  = msk ? xv : (xyk[1] + alpha * rb);
    float num = dk1*e2 + 2.f*sk*et + dk*om*om;
    float ld  = msk ? 0.f : __builtin_amdgcn_logf(sk*sk*num*rb*rb) * LN2;

    out[gr*16 + t] = yv;
    ldv[pp] = ld;
  }

  // per-row logdet: 8 t-lanes are adjacent -> 3-step shfl_xor reduction
  float s0 = ldv[0], s1 = ldv[1];
  #pragma unroll
  for (int m = 1; m < 8; m <<= 1){
    s0 += __shfl_xor(s0, m);
    s1 += __shfl_xor(s1, m);
  }
  if ((lane & 7) == 0){
    int r = tid >> 3;                    // 0..63
    out[(long)nrows*16 + row0 + r]      = s0;
    out[(long)nrows*16 + row0 + r + 64] = s1;
  }
}

extern "C" void kernel_launch(void* const* d_in, const int* in_sizes, int n_in,
                              void* d_out, int out_size, void* d_ws, size_t ws_size,
                              hipStream_t stream)
{
  const float* x    = (const float*)d_in[0];
  const float* W0   = (const float*)d_in[1];
  const float* b0   = (const float*)d_in[2];
  const float* W1   = (const float*)d_in[3];
  const float* b1   = (const float*)d_in[4];
  const float* Wout = (const float*)d_in[5];
  const float* bout = (const float*)d_in[6];
  float* out = (float*)d_out;
  __bf16* sw = (__bf16*)d_ws;

  int nrows = in_sizes[0] / 16;          // 524288
  int ntiles = nrows / ROWS;             // 4096

  prep_kernel<<<(SW_TOTAL + 255)/256, 256, 0, stream>>>(W0, W1, Wout, sw);
  fused_kernel<<<ntiles, 512, 0, stream>>>(x, b0, b1, bout, sw, out, nrows);
}

// Round 8
// 225.611 us; speedup vs baseline: 1.2239x; 1.0081x over previous
//
#include <hip/hip_runtime.h>
#include <hip/hip_bf16.h>

// CouplingSplineLayer fused kernel for MI355X (gfx950), round 8.
// R8 = R7 + G3 computed TRANSPOSED over a 192-column padded Wout'
// (n' = t*24 + p; col 23 of each 24-slot = zero weight/bias, done in prep).
// Every lane's 4 consecutive n' stay inside one t-slot (24 % 4 == 0), so all
// raw writes are clean bf16x4 b64 (same proven-even bank pattern as G1/G2) --
// kills G3's 48/wave ds_write_b16 scatter (the SQ_LDS_BANK_CONFLICT source),
// the col<184 predication and the /23 hack. LDS raw image = epilogue's
// 24-slot layout exactly; epilogue unchanged.

typedef __bf16 bf16x8 __attribute__((ext_vector_type(8)));
typedef __bf16 bf16x4v __attribute__((ext_vector_type(4)));
typedef float  f32x8 __attribute__((ext_vector_type(8)));
typedef float  f32x4 __attribute__((ext_vector_type(4)));
typedef float  f32x2 __attribute__((ext_vector_type(2)));

#define MFMA16(a,b,c) __builtin_amdgcn_mfma_f32_16x16x32_bf16((a),(b),(c),0,0,0)

#define SW_W1_OFF 8192      // W0: 1 kb * 16 tiles * 512
#define SW_WO_OFF 73728     // W1: 8 kb * 16 tiles * 512
#define SW_TOTAL  122880    // Wout': 8 kb * 12 tiles * 512 (192 padded cols)
// float bout'[192] lives at d_ws + SW_TOTAL*2 bytes

#define ROWS    128
#define HSTRIDE 264         // h row stride in bf16 (528 B: 16B-aligned)
#define LOG2E   1.44269504f
#define LN2     0.69314718f
#define SPCONST 0.7806568f      // log(exp(1-1e-4)-1) * log2e
#define ZSENT  (-0.00015680f)   // raw-z sentinel whose softplus-chain -> d = 1

__global__ void prep_kernel(const float* __restrict__ W0,
                            const float* __restrict__ W1,
                            const float* __restrict__ Wout,
                            const float* __restrict__ bout,
                            __bf16* __restrict__ sw)
{
  int i = blockIdx.x * 256 + threadIdx.x;
  if (i >= SW_TOTAL + 192) return;
  if (i >= SW_TOTAL){                      // bout'[192] remap (float, *log2e)
    int np = i - SW_TOTAL;
    int t = np / 24, p = np % 24;
    float* boutp = (float*)(sw + SW_TOTAL);
    boutp[np] = (p < 23) ? bout[t*23 + p] * LOG2E : 0.f;
    return;
  }
  const float* src; int K, N, NT, li;
  bool wo = false;
  if (i < SW_W1_OFF)      { src = W0;   K = 8;   N = 256; NT = 16; li = i; }
  else if (i < SW_WO_OFF) { src = W1;   K = 256; N = 256; NT = 16; li = i - SW_W1_OFF; }
  else { src = Wout; K = 256; N = 184; NT = 12; li = i - SW_WO_OFF; wo = true; }
  int j    = li & 7;
  int l    = (li >> 3) & 63;
  int rest = li >> 9;
  int nt   = rest % NT;
  int kb   = rest / NT;
  int k = kb * 32 + ((l >> 4) << 3) + j;
  int n = nt * 16 + (l & 15);
  float v;
  if (wo){
    int t = n / 24, p = n % 24;            // n is padded col n' in 0..191
    v = (p < 23 && k < K) ? Wout[k*184 + t*23 + p] * LOG2E : 0.f;
  } else {
    v = (k < K && n < N) ? src[k * N + n] : 0.f;
  }
  sw[i] = (__bf16)v;
}

__device__ __forceinline__ bf16x4v relu_cvt4(f32x4 acc, float4 bb){
  f32x4 s;
  s[0] = acc[0] + bb.x; s[1] = acc[1] + bb.y;
  s[2] = acc[2] + bb.z; s[3] = acc[3] + bb.w;
  f32x4 z = {0.f, 0.f, 0.f, 0.f};
  s = __builtin_elementwise_max(s, z);
  return __builtin_convertvector(s, bf16x4v);   // v_cvt_pk_bf16_f32 x2
}

__device__ __forceinline__ bf16x4v add_cvt4(f32x4 acc, float4 bb){
  f32x4 s;
  s[0] = acc[0] + bb.x; s[1] = acc[1] + bb.y;
  s[2] = acc[2] + bb.z; s[3] = acc[3] + bb.w;
  return __builtin_convertvector(s, bf16x4v);
}

__global__ __launch_bounds__(512, 4)
void fused_kernel(const float* __restrict__ x,
                  const float* __restrict__ b0v,
                  const float* __restrict__ b1v,
                  const __bf16* __restrict__ sw,
                  float* __restrict__ out,
                  int nrows)
{
  // ONE aliased buffer: h1 -> h2 (in place) -> raw. 128 x 264 bf16 = 66 KB.
  __shared__ __align__(16) unsigned char smem[ROWS * HSTRIDE * 2];
  __bf16* hbuf = (__bf16*)smem;
  __bf16* rawb = hbuf;

  const int tid  = threadIdx.x;
  const int wave = tid >> 6;
  const int lane = tid & 63;
  const int quad = lane >> 4;
  const int l16  = lane & 15;
  const int row0 = blockIdx.x * ROWS;

  const __bf16* swW1 = sw + SW_W1_OFF;
  const __bf16* swWo = sw + SW_WO_OFF;
  const float* boutp = (const float*)(sw + SW_TOTAL);
  const f32x4 z4 = {0.f, 0.f, 0.f, 0.f};

  // ---- x2 passthrough: 2 float4 per row on 256 threads (independent)
  if (tid < 2*ROWS){
    int r = tid >> 1, hf = tid & 1;
    long g = (long)row0 + r;
    *(float4*)(out + g*16 + 8 + hf*4) = *(const float4*)(x + g*16 + 8 + hf*4);
  }

  const int mq = wave >> 1;   // m-quarter (4 m-tiles) for G1/G2
  const int nh = wave & 1;    // batch-half (4 batch-tiles) for G1/G2

  // ---- GEMM1 (transposed): h1[b][m] = relu(sum_k W0[k][m]*x2[b][k] + b0[m])
  {
    bf16x8 bfr[4];
    #pragma unroll
    for (int nt = 0; nt < 4; nt++){
      bf16x8 b = {};                       // k=quad*8+j; only quad 0 (k<8) real
      if (quad == 0){
        const float* xp = x + (long)(row0 + (nh*4 + nt)*16 + l16)*16 + 8;
        float4 u = *(const float4*)xp;
        float4 v = *(const float4*)(xp + 4);
        f32x8 xf; xf[0]=u.x; xf[1]=u.y; xf[2]=u.z; xf[3]=u.w;
                  xf[4]=v.x; xf[5]=v.y; xf[6]=v.z; xf[7]=v.w;
        b = __builtin_convertvector(xf, bf16x8);
      }
      bfr[nt] = b;
    }
    #pragma unroll
    for (int mi = 0; mi < 4; mi++){
      int mt = mq*4 + mi;
      bf16x8 a = *(const bf16x8*)(sw + (mt*64 + lane)*8);
      float4 bb = *(const float4*)(b0v + mt*16 + quad*4);
      #pragma unroll
      for (int nt = 0; nt < 4; nt++){
        f32x4 acc = MFMA16(a, bfr[nt], z4);
        *(bf16x4v*)(hbuf + ((nh*4+nt)*16 + l16)*HSTRIDE + mt*16 + quad*4) = relu_cvt4(acc, bb);
      }
    }
  }
  __syncthreads();

  // ---- GEMM2 (transposed): h2[b][m] = relu(sum_k W1[k][m]*h1[b][k] + b1[m])
  {
    f32x4 acc[4][4];                       // [mi][bt]
    #pragma unroll
    for (int mi=0;mi<4;mi++)
      #pragma unroll
      for (int bt=0;bt<4;bt++) acc[mi][bt] = z4;
    #pragma unroll
    for (int kb=0;kb<8;kb++){
      bf16x8 hf[4];
      #pragma unroll
      for (int bt=0;bt<4;bt++)
        hf[bt] = *(const bf16x8*)(hbuf + ((nh*4+bt)*16 + l16)*HSTRIDE + kb*32 + quad*8);
      #pragma unroll
      for (int mi=0;mi<4;mi++){
        bf16x8 a = *(const bf16x8*)(swW1 + ((kb*16 + mq*4 + mi)*64 + lane)*8);
        #pragma unroll
        for (int bt=0;bt<4;bt++)
          acc[mi][bt] = MFMA16(a, hf[bt], acc[mi][bt]);
      }
    }
    __syncthreads();
    #pragma unroll
    for (int mi=0;mi<4;mi++){
      int mt = mq*4 + mi;
      float4 bb = *(const float4*)(b1v + mt*16 + quad*4);
      #pragma unroll
      for (int bt=0;bt<4;bt++)
        *(bf16x4v*)(hbuf + ((nh*4+bt)*16 + l16)*HSTRIDE + mt*16 + quad*4) = relu_cvt4(acc[mi][bt], bb);
    }
  }
  __syncthreads();

  // ---- GEMM3 (TRANSPOSED, 192 padded cols): raw2[b][n'] = sum_k Wout'[k][n']*h2[b][k] + bout'
  // wave = (nc: 3 n'-tiles) x (mh half of batch: 4 tiles in registers)
  {
    const int nc = wave & 3;
    const int mh = wave >> 2;
    f32x4 acc[4][3];                       // [bt][mi]
    #pragma unroll
    for (int bt=0;bt<4;bt++)
      #pragma unroll
      for (int mi=0;mi<3;mi++) acc[bt][mi] = z4;
    #pragma unroll
    for (int kb=0;kb<8;kb++){
      bf16x8 hf[4];
      #pragma unroll
      for (int bt=0;bt<4;bt++)
        hf[bt] = *(const bf16x8*)(hbuf + ((mh*4+bt)*16 + l16)*HSTRIDE + kb*32 + quad*8);
      #pragma unroll
      for (int mi=0;mi<3;mi++){
        bf16x8 a = *(const bf16x8*)(swWo + ((kb*12 + nc*3 + mi)*64 + lane)*8);
        #pragma unroll
        for (int bt=0;bt<4;bt++)
          acc[bt][mi] = MFMA16(a, hf[bt], acc[bt][mi]);
      }
    }
    __syncthreads();
    #pragma unroll
    for (int mi=0;mi<3;mi++){
      int mt = nc*3 + mi;
      float4 bb = *(const float4*)(boutp + mt*16 + quad*4);
      #pragma unroll
      for (int bt=0;bt<4;bt++){
        int row = (mh*4+bt)*16 + l16;
        *(bf16x4v*)(rawb + row*HSTRIDE + mt*16 + quad*4) = add_cvt4(acc[bt][mi], bb);
      }
    }
  }
  __syncthreads();

  // ---- RQ spline epilogue: 1024 tasks, 2/thread; ldet via shfl_xor
  float ldv[2];
  #pragma unroll
  for (int pp = 0; pp < 2; pp++){
    int p   = tid + pp*512;
    int row = p >> 3;
    int t   = p & 7;
    long gr = row0 + row;
    float xv = x[gr*16 + t];

    const __bf16* rr = rawb + row*HSTRIDE + t*24;   // 48B slots, b128-aligned
    bf16x8 v0 = *(const bf16x8*)(rr);
    bf16x8 v1 = *(const bf16x8*)(rr + 8);
    bf16x8 v2 = *(const bf16x8*)(rr + 16);

    // raw2 already in log2-units: 2^raw2 = e^raw exactly
    f32x2 ewh[8];
    f32x2 sum = {0.f, 0.f};
    #pragma unroll
    for (int i=0;i<8;i++){
      f32x2 e;
      e[0] = __builtin_amdgcn_exp2f((float)v0[i]);
      e[1] = __builtin_amdgcn_exp2f((float)v1[i]);
      ewh[i] = e; sum += e;
    }
    f32x2 scale;
    scale[0] = 1.9984f * __builtin_amdgcn_rcpf(sum[0]);
    scale[1] = 1.9984f * __builtin_amdgcn_rcpf(sum[1]);
    const f32x2 off2 = {2e-4f, 2e-4f};

    bool msk = (xv <= -0.999f) || (xv >= 0.999f);
    float xin = msk ? 0.f : xv;

    // packed scan; sentinel-select raw z for the two needed derivatives
    f32x2 whi = ewh[0]*scale + off2;
    f32x2 ec; ec[0] = -1.f + whi[0]; ec[1] = -1.f + whi[1];
    f32x2 xyk = {-1.f, -1.f};
    f32x2 whk = whi;
    float zk = ZSENT, zk1 = (float)v2[0];
    #pragma unroll
    for (int i=1;i<8;i++){
      whi = ewh[i]*scale + off2;
      bool le = (ec[0] <= xin);
      xyk = le ? ec : xyk;
      whk = le ? whi : whk;
      zk  = le ? (float)v2[i-1] : zk;
      zk1 = le ? ((i==7) ? ZSENT : (float)v2[i]) : zk1;
      ec += whi;
    }

    // softplus (base-2) only for the two selected derivatives
    float za = zk + SPCONST, zb = zk1 + SPCONST;
    float dk  = (fmaxf(za,0.f) + __builtin_amdgcn_logf(1.f + __builtin_amdgcn_exp2f(-fabsf(za))))*LN2 + 1e-4f;
    float dk1 = (fmaxf(zb,0.f) + __builtin_amdgcn_logf(1.f + __builtin_amdgcn_exp2f(-fabsf(zb))))*LN2 + 1e-4f;

    float rwk = __builtin_amdgcn_rcpf(whk[0]);
    float sk  = whk[1] * rwk;
    float eps = (xin - xyk[0]) * rwk;
    float om  = 1.f - eps;
    float et  = eps * om;
    float e2  = eps * eps;
    float beta  = sk + (dk1 + dk - 2.f*sk) * et;
    float rb    = __builtin_amdgcn_rcpf(beta);
    float alpha = whk[1] * (sk*e2 + dk*et);
    float yv  = msk ? xv : (xyk[1] + alpha * rb);
    float num = dk1*e2 + 2.f*sk*et + dk*om*om;
    float ld  = msk ? 0.f : __builtin_amdgcn_logf(sk*sk*num*rb*rb) * LN2;

    out[gr*16 + t] = yv;
    ldv[pp] = ld;
  }

  // per-row logdet: 8 t-lanes are adjacent -> 3-step shfl_xor reduction
  float s0 = ldv[0], s1 = ldv[1];
  #pragma unroll
  for (int m = 1; m < 8; m <<= 1){
    s0 += __shfl_xor(s0, m);
    s1 += __shfl_xor(s1, m);
  }
  if ((lane & 7) == 0){
    int r = tid >> 3;                    // 0..63
    out[(long)nrows*16 + row0 + r]      = s0;
    out[(long)nrows*16 + row0 + r + 64] = s1;
  }
}

extern "C" void kernel_launch(void* const* d_in, const int* in_sizes, int n_in,
                              void* d_out, int out_size, void* d_ws, size_t ws_size,
                              hipStream_t stream)
{
  const float* x    = (const float*)d_in[0];
  const float* W0   = (const float*)d_in[1];
  const float* b0   = (const float*)d_in[2];
  const float* W1   = (const float*)d_in[3];
  const float* b1   = (const float*)d_in[4];
  const float* Wout = (const float*)d_in[5];
  const float* bout = (const float*)d_in[6];
  float* out = (float*)d_out;
  __bf16* sw = (__bf16*)d_ws;

  int nrows = in_sizes[0] / 16;          // 524288
  int ntiles = nrows / ROWS;             // 4096

  prep_kernel<<<(SW_TOTAL + 192 + 255)/256, 256, 0, stream>>>(W0, W1, Wout, bout, sw);
  fused_kernel<<<ntiles, 512, 0, stream>>>(x, b0, b1, sw, out, nrows);
}